// Round 6
// baseline (327.951 us; speedup 1.0000x reference)
//
#include <hip/hip_runtime.h>
#include <math.h>

// ---------------------------------------------------------------------------
// SGCN forward — CSR pull aggregation + MFMA dense layers.
//
// R10 change: each gemm block consumes only its own 64 nodes' aggregates, so
// the agg->gemm global round-trip (25.6MB ag written by agg_k, re-read by
// gemm_k; 51MB/layer) is unnecessary. layer_k fuses them PER BLOCK with
// sequential phases (not per-node interleave, which was R7's mistake):
//   wave w: gather its 16 nodes (8-stream h8 structure, same MLP as agg_k)
//           -> aggregate written straight into A_lds -> stage own x rows
//           -> barrier -> identical MFMA epilogue (mfma_f32_16x16x32_f16).
// Also: bscan_k folded into scatter_k (each block scans the 391 bucket
// counts in LDS, ~us, redundantly); cvt_k+prep_k fused. Launches 9 -> 5.
// CSR build (bucket LDS-rank sort, zero per-edge global atomics) per R9.
// ---------------------------------------------------------------------------

typedef _Float16 h4 __attribute__((ext_vector_type(4)));
typedef _Float16 h8 __attribute__((ext_vector_type(8)));
typedef float f32x4 __attribute__((ext_vector_type(4)));

__device__ inline h8 shflx8(h8 v, int m) {
    int4 i = __builtin_bit_cast(int4, v);
    i.x = __shfl_xor(i.x, m);
    i.y = __shfl_xor(i.y, m);
    i.z = __shfl_xor(i.z, m);
    i.w = __shfl_xor(i.w, m);
    return __builtin_bit_cast(h8, i);
}

__device__ inline float fast_tanh(float v) {
    float e = __expf(2.0f * v);
    return 1.0f - 2.0f / (e + 1.0f);
}

// ------------------------------- CSR build ---------------------------------
// Bucket = 512 consecutive flattened dst ids (2n space: pos then neg).
// Record = (nd & 511) << 17 | src   (src < 2^17, rel < 2^9 -> 26 bits).

#define BSHIFT 9
#define BSIZE  512
#define NBMAX  512
#define CAP    8192   // per-bucket record capacity; mean 6400, +22 sigma

__global__ void __launch_bounds__(256) bucket_k(
    const int* __restrict__ pos, const int* __restrict__ neg,
    int* __restrict__ pcnt, unsigned* __restrict__ ebuf,
    int E, int n, int nb)
{
    __shared__ int cnt[NBMAX], gbase[NBMAX];
    const int K = 32;
    int tid = threadIdx.x;
    int base = blockIdx.x * (256 * K);

    for (int i = tid; i < nb; i += 256) cnt[i] = 0;
    __syncthreads();

    unsigned val[K], pr[K];       // pr = part<<13 | rank (rank <= 8191)
    #pragma unroll
    for (int k = 0; k < K; ++k) {
        int e = base + k * 256 + tid;
        pr[k] = 0xFFFFFFFFu;
        if (e < 2 * E) {
            int nd, sr;
            if (e < E) { nd = pos[E + e];                 sr = pos[e]; }
            else       { int ee = e - E; nd = n + neg[E + ee]; sr = neg[ee]; }
            int p = nd >> BSHIFT;
            val[k] = ((unsigned)(nd & (BSIZE - 1)) << 17) | (unsigned)sr;
            int rank = atomicAdd(&cnt[p], 1);
            pr[k] = ((unsigned)p << 13) | (unsigned)rank;
        }
    }
    __syncthreads();
    for (int i = tid; i < nb; i += 256) {
        int c = cnt[i];
        gbase[i] = c ? atomicAdd(&pcnt[i], c) : 0;
    }
    __syncthreads();
    #pragma unroll
    for (int k = 0; k < K; ++k) {
        if (pr[k] != 0xFFFFFFFFu) {
            int p = (int)(pr[k] >> 13);
            int off = gbase[p] + (int)(pr[k] & 0x1FFFu);
            if (off < CAP) ebuf[(size_t)p * CAP + off] = val[k];
        }
    }
}

// One block per bucket. Inline scan of all bucket counts (replaces bscan_k),
// then: LDS histogram -> scan -> dense cur write -> LDS staging of col
// segment -> contiguous global stream-out.
__global__ void __launch_bounds__(256) scatter_k(
    const unsigned* __restrict__ ebuf, const int* __restrict__ pcnt,
    int* __restrict__ cur, int* __restrict__ col, int n, int nb)
{
    __shared__ int lcnt[BSIZE], lbase[BSIZE], sc[256], bb[NBMAX];
    __shared__ int lcol[CAP];
    int p = blockIdx.x;
    int tid = threadIdx.x;
    int n2 = 2 * n;
    int lo = p << BSHIFT;
    int nn = min(BSIZE, n2 - lo);
    int cnt = min(pcnt[p], CAP);
    const unsigned* buf = ebuf + (size_t)p * CAP;

    // inline exclusive scan of pcnt[0..nb) (2 elements per thread)
    {
        int a0 = (2 * tid     < nb) ? pcnt[2 * tid]     : 0;
        int a1 = (2 * tid + 1 < nb) ? pcnt[2 * tid + 1] : 0;
        int s = a0 + a1;
        sc[tid] = s;
        __syncthreads();
        for (int off = 1; off < 256; off <<= 1) {
            int t = (tid >= off) ? sc[tid - off] : 0;
            __syncthreads();
            sc[tid] += t;
            __syncthreads();
        }
        int excl = sc[tid] - s;
        bb[2 * tid] = excl;
        bb[2 * tid + 1] = excl + a0;
    }

    lcnt[tid] = 0; lcnt[tid + 256] = 0;
    __syncthreads();
    for (int i = tid; i < cnt; i += 256) {
        unsigned v = buf[i];
        atomicAdd(&lcnt[v >> 17], 1);
    }
    __syncthreads();
    int a0 = lcnt[2 * tid], a1 = lcnt[2 * tid + 1];
    int s = a0 + a1;
    sc[tid] = s;
    __syncthreads();
    for (int off = 1; off < 256; off <<= 1) {
        int t = (tid >= off) ? sc[tid - off] : 0;
        __syncthreads();
        sc[tid] += t;
        __syncthreads();
    }
    int excl = sc[tid] - s;
    lbase[2 * tid] = excl;
    lbase[2 * tid + 1] = excl + a0;
    __syncthreads();
    int gb = bb[p];
    for (int i = tid; i < nn; i += 256)            // inclusive prefix -> cur
        cur[lo + i] = gb + lbase[i] + lcnt[i];
    __syncthreads();
    for (int i = tid; i < cnt; i += 256) {         // place into LDS staging
        unsigned v = buf[i];
        int rel = (int)(v >> 17);
        int slot = atomicAdd(&lbase[rel], 1);
        lcol[slot] = (int)(v & 0x1FFFFu);
    }
    __syncthreads();
    for (int t = tid; t < cnt; t += 256)           // dense stream-out
        col[gb + t] = lcol[t];
}

// ------------------- x -> fp16  +  weight fragment packing ------------------
// B (192x64) packed in MFMA fragment order: frag (kk,nt), lane l, elem j
// holds B[kk*32 + (l>>4)*8 + j][nt*16 + (l&15)]. Same (l,j)->k map as the
// A-side LDS read, so the contraction is layout-consistent.
// A1 row = [aggP(x) 0..63 | aggN(x) 64..127 | x 128..191]
// A2 row = [Mp(zp) 0..31 | Mp(zn) 32..63 | Mn(zp) 64..95 | Mn(zn) 96..127 |
//           zp 128..159 | zn 160..191]

__device__ inline float b1map(const float* W1p, const float* W1n, int k, int c)
{
    if (c < 32) {
        if (k < 64)   return W1p[k * 32 + c];            // aggP -> W1p rows 0..63
        if (k >= 128) return W1p[(k - 64) * 32 + c];     // x    -> W1p rows 64..127
        return 0.0f;
    } else {
        int cn = c - 32;
        if (k >= 64)  return W1n[(k - 64) * 32 + cn];    // aggN rows 0..63, x rows 64..127
        return 0.0f;
    }
}

__device__ inline float b2map(const float* W2p, const float* W2n, int k, int c)
{
    if (c < 32) {
        if (k < 32)               return W2p[k * 32 + c];              // Mp(zp)
        if (k >= 96 && k < 128)   return W2p[(k - 96 + 32) * 32 + c];  // Mn(zn)
        if (k >= 128 && k < 160)  return W2p[(k - 128 + 64) * 32 + c]; // zp
        return 0.0f;
    } else {
        int cn = c - 32;
        if (k >= 32 && k < 64)    return W2n[(k - 32) * 32 + cn];       // Mp(zn)
        if (k >= 64 && k < 96)    return W2n[(k - 64 + 32) * 32 + cn];  // Mn(zp)
        if (k >= 160)             return W2n[(k - 160 + 64) * 32 + cn]; // zn
        return 0.0f;
    }
}

__global__ void __launch_bounds__(256) cvtprep_k(
    const float4* __restrict__ x, h4* __restrict__ xh, int n4, int cvtBlocks,
    const float* __restrict__ W1p, const float* __restrict__ W1n,
    const float* __restrict__ W2p, const float* __restrict__ W2n,
    _Float16* __restrict__ Bpack)
{
    if ((int)blockIdx.x < cvtBlocks) {
        int i = blockIdx.x * 256 + threadIdx.x;
        if (i < n4) {
            float4 v = x[i];
            h4 o = { (_Float16)v.x, (_Float16)v.y, (_Float16)v.z, (_Float16)v.w };
            xh[i] = o;
        }
        return;
    }
    int slot = (blockIdx.x - cvtBlocks) * 256 + threadIdx.x;   // 0..3071
    if (slot >= 2 * 24 * 64) return;
    int mat  = slot / (24 * 64);
    int rem  = slot % (24 * 64);
    int fg   = rem / 64;          // kk*4 + nt
    int lane = rem % 64;
    int kk = fg >> 2, nt = fg & 3;
    int g = lane >> 4, m = lane & 15;
    _Float16* dst = Bpack + (size_t)slot * 8;
    int c = nt * 16 + m;
    #pragma unroll
    for (int j = 0; j < 8; ++j) {
        int k = kk * 32 + g * 8 + j;
        float v = mat ? b2map(W2p, W2n, k, c) : b1map(W1p, W1n, k, c);
        dst[j] = (_Float16)v;
    }
}

// ------------------------- fused agg + GEMM layer ---------------------------
// 64 nodes/block, 4 waves. Phase 1 (per wave, its own 16 rows): gather with
// 8 streams (groups 0-3 pos stride-4, 4-7 neg; lane&7 = h8 chunk of row),
// reduce shfl_xor(8)+shfl_xor(16), aggregate written straight to A_lds;
// own feat rows staged alongside. Phase 2: MFMA epilogue.
// A row k-order matches prep_k's fragment map. D layout (verified):
// col = lane&15, row = (lane>>4)*4 + reg.

#define ROWP 200

__global__ void __launch_bounds__(256) layer_k(
    const h8* __restrict__ feat8,
    const int* __restrict__ cur, const int* __restrict__ col,
    const h8* __restrict__ Bp,
    const float* __restrict__ bp, const float* __restrict__ bn,
    float* __restrict__ outf, _Float16* __restrict__ outh,
    int f32out, int n)
{
    __shared__ _Float16 A_lds[64 * ROWP];   // 25.6 KB
    int tid = threadIdx.x;
    int base = blockIdx.x * 64;
    int w = tid >> 6, lane = tid & 63;

    // ---- phase 1a: gather (wave w owns A_lds rows w*16 .. w*16+15) ----
    {
        int g = lane >> 3, f = lane & 7;
        int list = g >> 2;            // 0 = pos, 1 = neg
        int sub = g & 3;              // stride-4 phase
        for (int t = 0; t < 16; ++t) {
            int node = base + w * 16 + t;
            if (node >= n) break;                 // wave-uniform
            int idx = list ? n + node : node;
            int r0 = idx ? cur[idx - 1] : 0;
            int r1 = cur[idx];
            h8 acc = {};
            #pragma unroll 2
            for (int it = r0 + sub; it < r1; it += 4)
                acc = acc + feat8[(unsigned)(col[it] * 8 + f)];
            acc = acc + shflx8(acc, 8);           // combine sub pairs
            acc = acc + shflx8(acc, 16);          // combine quads
            _Float16 inv = (_Float16)(1.0f / (float)max(r1 - r0, 1));
            h8 iv = { inv, inv, inv, inv, inv, inv, inv, inv };
            acc = acc * iv;
            if (sub == 0)
                *(h8*)&A_lds[(w * 16 + t) * ROWP + list * 64 + f * 8] = acc;
        }
    }
    // ---- phase 1b: stage own feat rows (k = 128..191) ----
    for (int ch = lane; ch < 16 * 8; ch += 64) {
        int t = ch >> 3, pch = ch & 7;
        int row = base + w * 16 + t;
        if (row < n)
            *(h8*)&A_lds[(w * 16 + t) * ROWP + 128 + pch * 8] =
                feat8[(size_t)row * 8 + pch];
    }
    __syncthreads();

    // ---- phase 2: MFMA ----
    int m = lane & 15, g4 = lane >> 4;
    h8 a[6];
    #pragma unroll
    for (int kk = 0; kk < 6; ++kk)
        a[kk] = *(const h8*)&A_lds[(w * 16 + m) * ROWP + kk * 32 + g4 * 8];

    #pragma unroll
    for (int nt = 0; nt < 4; ++nt) {
        f32x4 acc = { 0.f, 0.f, 0.f, 0.f };
        #pragma unroll
        for (int kk = 0; kk < 6; ++kk) {
            h8 b = Bp[(kk * 4 + nt) * 64 + lane];
            acc = __builtin_amdgcn_mfma_f32_16x16x32_f16(a[kk], b, acc, 0, 0, 0);
        }
        int colc = nt * 16 + m;
        float bias = (colc < 32) ? bp[colc] : bn[colc - 32];
        #pragma unroll
        for (int reg = 0; reg < 4; ++reg) {
            int node = base + w * 16 + g4 * 4 + reg;
            if (node < n) {
                float val = fast_tanh(acc[reg] + bias);
                if (f32out) outf[(size_t)node * 64 + colc] = val;
                else        outh[(size_t)node * 64 + colc] = (_Float16)val;
            }
        }
    }
}

extern "C" void kernel_launch(void* const* d_in, const int* in_sizes, int n_in,
                              void* d_out, int out_size, void* d_ws, size_t ws_size,
                              hipStream_t stream)
{
    const float* x   = (const float*)d_in[0];
    const float* W1p = (const float*)d_in[1];
    const float* b1p = (const float*)d_in[2];
    const float* W1n = (const float*)d_in[3];
    const float* b1n = (const float*)d_in[4];
    const float* W2p = (const float*)d_in[5];
    const float* b2p = (const float*)d_in[6];
    const float* W2n = (const float*)d_in[7];
    const float* b2n = (const float*)d_in[8];
    const int*   pos = (const int*)d_in[9];
    const int*   neg = (const int*)d_in[10];

    int n = in_sizes[0] / 64;       // 100000
    int E = in_sizes[9] / 2;        // 1250000
    int n2 = 2 * n;
    int nb = (n2 + BSIZE - 1) / BSIZE;   // 391 buckets

    // ws: pcnt[512] | cur[2n] | col[2E] | Bpack[2*24*64*8 h] | xh[n*64 h] |
    //     U = max(ebuf nb*CAP u32, zh n*64 h)
    int*      pcnt  = (int*)d_ws;
    int*      cur   = pcnt + NBMAX;
    int*      col   = cur + n2;
    _Float16* Bpack = (_Float16*)(col + 2 * (size_t)E);
    _Float16* xh    = Bpack + 2 * 24 * 64 * 8;
    unsigned* ebuf  = (unsigned*)(xh + (size_t)n * 64);
    _Float16* zh    = (_Float16*)ebuf;            // aliases ebuf (dead after scatter)

    hipMemsetAsync(pcnt, 0, NBMAX * sizeof(int), stream);

    int bblocks = (2 * E + 8191) / 8192;
    bucket_k<<<bblocks, 256, 0, stream>>>(pos, neg, pcnt, ebuf, E, n, nb);
    scatter_k<<<nb, 256, 0, stream>>>(ebuf, pcnt, cur, col, n, nb);

    int n4 = n * 16;
    int cvtBlocks = (n4 + 255) / 256;
    cvtprep_k<<<cvtBlocks + 12, 256, 0, stream>>>(
        (const float4*)x, (h4*)xh, n4, cvtBlocks, W1p, W1n, W2p, W2n, Bpack);

    int lblocks = (n + 63) / 64;
    // layer 1: gather(x) + gemm(A1=[agP|agN|x]) -> zh (fp16)
    layer_k<<<lblocks, 256, 0, stream>>>((const h8*)xh, cur, col,
                                         (const h8*)Bpack, b1p, b1n,
                                         nullptr, zh, 0, n);
    // layer 2: gather(z) + gemm(A2=[Mp|Mn|z]) -> out (fp32)
    layer_k<<<lblocks, 256, 0, stream>>>((const h8*)zh, cur, col,
                                         (const h8*)(Bpack + 24 * 64 * 8),
                                         b2p, b2n, (float*)d_out, nullptr, 1, n);
}

// Round 7
// 274.503 us; speedup vs baseline: 1.1947x; 1.1947x over previous
//
#include <hip/hip_runtime.h>
#include <math.h>

// ---------------------------------------------------------------------------
// SGCN forward — CSR pull aggregation + MFMA dense layers.
//
// R11: revert R10's agg+gemm fusion (it collapsed gather oversubscription:
// occ 37%, 95 streams/CU vs 186 -> 89us/layer). Back to R9's split, plus:
//   * agg_k 16 streams/wave (4-lane groups, 2 h8 chunks/lane, reduce
//     shfl_xor 4/8/16): outstanding bytes/wave 1KB -> 2KB, mean chain
//     3.1 -> 1.6 iters. If this doesn't move ~46us -> fabric ceiling.
//   * mega_k: bucket + x->fp16 cvt + weight prep in ONE grid (block-range
//     dispatch; independent work overlaps bucket's LDS-atomic phase).
//   * scatter_k keeps R10's inline bscan (kernel count 9 -> 6).
// GEMM (mfma 16x16x32 f16, f32 accum, fragment-packed B) unchanged from R9.
// ---------------------------------------------------------------------------

typedef _Float16 h4 __attribute__((ext_vector_type(4)));
typedef _Float16 h8 __attribute__((ext_vector_type(8)));
typedef float f32x4 __attribute__((ext_vector_type(4)));

__device__ inline h8 shflx8(h8 v, int m) {
    int4 i = __builtin_bit_cast(int4, v);
    i.x = __shfl_xor(i.x, m);
    i.y = __shfl_xor(i.y, m);
    i.z = __shfl_xor(i.z, m);
    i.w = __shfl_xor(i.w, m);
    return __builtin_bit_cast(h8, i);
}

__device__ inline float fast_tanh(float v) {
    float e = __expf(2.0f * v);
    return 1.0f - 2.0f / (e + 1.0f);
}

// ------------------------------- CSR build ---------------------------------
// Bucket = 512 consecutive flattened dst ids (2n space: pos then neg).
// Record = (nd & 511) << 17 | src   (src < 2^17, rel < 2^9 -> 26 bits).

#define BSHIFT 9
#define BSIZE  512
#define NBMAX  512
#define CAP    8192   // per-bucket record capacity; mean 6400, +22 sigma

// ---- weight fragment maps (B 192x64 packed in MFMA fragment order) --------
// frag (kk,nt), lane l, elem j holds B[kk*32 + (l>>4)*8 + j][nt*16 + (l&15)].
// A1 row = [aggP(x) 0..63 | aggN(x) 64..127 | x 128..191]
// A2 row = [Mp(zp) 0..31 | Mp(zn) 32..63 | Mn(zp) 64..95 | Mn(zn) 96..127 |
//           zp 128..159 | zn 160..191]

__device__ inline float b1map(const float* W1p, const float* W1n, int k, int c)
{
    if (c < 32) {
        if (k < 64)   return W1p[k * 32 + c];            // aggP -> W1p rows 0..63
        if (k >= 128) return W1p[(k - 64) * 32 + c];     // x    -> W1p rows 64..127
        return 0.0f;
    } else {
        int cn = c - 32;
        if (k >= 64)  return W1n[(k - 64) * 32 + cn];    // aggN rows 0..63, x rows 64..127
        return 0.0f;
    }
}

__device__ inline float b2map(const float* W2p, const float* W2n, int k, int c)
{
    if (c < 32) {
        if (k < 32)               return W2p[k * 32 + c];              // Mp(zp)
        if (k >= 96 && k < 128)   return W2p[(k - 96 + 32) * 32 + c];  // Mn(zn)
        if (k >= 128 && k < 160)  return W2p[(k - 128 + 64) * 32 + c]; // zp
        return 0.0f;
    } else {
        int cn = c - 32;
        if (k >= 32 && k < 64)    return W2n[(k - 32) * 32 + cn];       // Mp(zn)
        if (k >= 64 && k < 96)    return W2n[(k - 64 + 32) * 32 + cn];  // Mn(zp)
        if (k >= 160)             return W2n[(k - 160 + 64) * 32 + cn]; // zn
        return 0.0f;
    }
}

// ---- merged: bucket (blocks [0,bblocks)) | cvt | prep ----------------------

__global__ void __launch_bounds__(256) mega_k(
    const int* __restrict__ pos, const int* __restrict__ neg,
    int* __restrict__ pcnt, unsigned* __restrict__ ebuf,
    int E, int n, int nb, int bblocks,
    const float4* __restrict__ x, h4* __restrict__ xh, int n4, int cvtBlocks,
    const float* __restrict__ W1p, const float* __restrict__ W1n,
    const float* __restrict__ W2p, const float* __restrict__ W2n,
    _Float16* __restrict__ Bpack)
{
    int tid = threadIdx.x;
    int bid = blockIdx.x;

    if (bid >= bblocks) {
        int cb = bid - bblocks;
        if (cb < cvtBlocks) {                       // ---- x -> fp16 ----
            int i = cb * 256 + tid;
            if (i < n4) {
                float4 v = x[i];
                h4 o = { (_Float16)v.x, (_Float16)v.y, (_Float16)v.z, (_Float16)v.w };
                xh[i] = o;
            }
        } else {                                    // ---- weight prep ----
            int slot = (cb - cvtBlocks) * 256 + tid;   // 0..3071
            if (slot < 2 * 24 * 64) {
                int mat  = slot / (24 * 64);
                int rem  = slot % (24 * 64);
                int fg   = rem / 64;          // kk*4 + nt
                int lane = rem % 64;
                int kk = fg >> 2, nt = fg & 3;
                int g = lane >> 4, m = lane & 15;
                _Float16* dst = Bpack + (size_t)slot * 8;
                int c = nt * 16 + m;
                #pragma unroll
                for (int j = 0; j < 8; ++j) {
                    int k = kk * 32 + g * 8 + j;
                    float v = mat ? b2map(W2p, W2n, k, c) : b1map(W1p, W1n, k, c);
                    dst[j] = (_Float16)v;
                }
            }
        }
        return;
    }

    // ---- bucket ----
    __shared__ int cnt[NBMAX], gbase[NBMAX];
    const int K = 32;
    int base = bid * (256 * K);

    for (int i = tid; i < nb; i += 256) cnt[i] = 0;
    __syncthreads();

    unsigned val[K], pr[K];       // pr = part<<13 | rank (rank <= 8191)
    #pragma unroll
    for (int k = 0; k < K; ++k) {
        int e = base + k * 256 + tid;
        pr[k] = 0xFFFFFFFFu;
        if (e < 2 * E) {
            int nd, sr;
            if (e < E) { nd = pos[E + e];                 sr = pos[e]; }
            else       { int ee = e - E; nd = n + neg[E + ee]; sr = neg[ee]; }
            int p = nd >> BSHIFT;
            val[k] = ((unsigned)(nd & (BSIZE - 1)) << 17) | (unsigned)sr;
            int rank = atomicAdd(&cnt[p], 1);
            pr[k] = ((unsigned)p << 13) | (unsigned)rank;
        }
    }
    __syncthreads();
    for (int i = tid; i < nb; i += 256) {
        int c = cnt[i];
        gbase[i] = c ? atomicAdd(&pcnt[i], c) : 0;
    }
    __syncthreads();
    #pragma unroll
    for (int k = 0; k < K; ++k) {
        if (pr[k] != 0xFFFFFFFFu) {
            int p = (int)(pr[k] >> 13);
            int off = gbase[p] + (int)(pr[k] & 0x1FFFu);
            if (off < CAP) ebuf[(size_t)p * CAP + off] = val[k];
        }
    }
}

// One block per bucket. Inline scan of all bucket counts, then LDS histogram
// -> scan -> dense cur write -> LDS staging of col segment -> contiguous
// global stream-out.
__global__ void __launch_bounds__(256) scatter_k(
    const unsigned* __restrict__ ebuf, const int* __restrict__ pcnt,
    int* __restrict__ cur, int* __restrict__ col, int n, int nb)
{
    __shared__ int lcnt[BSIZE], lbase[BSIZE], sc[256], bb[NBMAX];
    __shared__ int lcol[CAP];
    int p = blockIdx.x;
    int tid = threadIdx.x;
    int n2 = 2 * n;
    int lo = p << BSHIFT;
    int nn = min(BSIZE, n2 - lo);
    int cnt = min(pcnt[p], CAP);
    const unsigned* buf = ebuf + (size_t)p * CAP;

    // inline exclusive scan of pcnt[0..nb) (2 elements per thread)
    {
        int a0 = (2 * tid     < nb) ? pcnt[2 * tid]     : 0;
        int a1 = (2 * tid + 1 < nb) ? pcnt[2 * tid + 1] : 0;
        int s = a0 + a1;
        sc[tid] = s;
        __syncthreads();
        for (int off = 1; off < 256; off <<= 1) {
            int t = (tid >= off) ? sc[tid - off] : 0;
            __syncthreads();
            sc[tid] += t;
            __syncthreads();
        }
        int excl = sc[tid] - s;
        bb[2 * tid] = excl;
        bb[2 * tid + 1] = excl + a0;
    }

    lcnt[tid] = 0; lcnt[tid + 256] = 0;
    __syncthreads();
    for (int i = tid; i < cnt; i += 256) {
        unsigned v = buf[i];
        atomicAdd(&lcnt[v >> 17], 1);
    }
    __syncthreads();
    int a0 = lcnt[2 * tid], a1 = lcnt[2 * tid + 1];
    int s = a0 + a1;
    sc[tid] = s;
    __syncthreads();
    for (int off = 1; off < 256; off <<= 1) {
        int t = (tid >= off) ? sc[tid - off] : 0;
        __syncthreads();
        sc[tid] += t;
        __syncthreads();
    }
    int excl = sc[tid] - s;
    lbase[2 * tid] = excl;
    lbase[2 * tid + 1] = excl + a0;
    __syncthreads();
    int gb = bb[p];
    for (int i = tid; i < nn; i += 256)            // inclusive prefix -> cur
        cur[lo + i] = gb + lbase[i] + lcnt[i];
    __syncthreads();
    for (int i = tid; i < cnt; i += 256) {         // place into LDS staging
        unsigned v = buf[i];
        int rel = (int)(v >> 17);
        int slot = atomicAdd(&lbase[rel], 1);
        lcol[slot] = (int)(v & 0x1FFFFu);
    }
    __syncthreads();
    for (int t = tid; t < cnt; t += 256)           // dense stream-out
        col[gb + t] = lcol[t];
}

// ------------------------------- aggregation -------------------------------
// One wave per node, 16 streams: stream s = lane>>2 (0-7 pos stride-8,
// 8-15 neg), lane f = lane&3; each lane accumulates h8 chunks f and f+4
// (group of 4 lanes covers the full 128B row, 2 loads/lane/edge).
// Reduce across strides with shfl_xor 4/8/16 (list bit 32 untouched).

__global__ void __launch_bounds__(256) agg_k(
    const h8* __restrict__ feat8,
    const int* __restrict__ cur, const int* __restrict__ col,
    h8* __restrict__ ag8, int n)
{
    int tid = threadIdx.x;
    int wave = tid >> 6, lane = tid & 63;
    int s = lane >> 2, f = lane & 3;
    int list = s >> 3;            // 0 = pos, 1 = neg
    int sub = s & 7;              // stride-8 phase

    int stride = gridDim.x * 4;
    for (int node = blockIdx.x * 4 + wave; node < n; node += stride) {
        int idx = list ? n + node : node;
        int r0 = idx ? cur[idx - 1] : 0;
        int r1 = cur[idx];

        h8 acc0 = {}, acc1 = {};
        #pragma unroll 2
        for (int it = r0 + sub; it < r1; it += 8) {
            unsigned srcb = (unsigned)col[it] * 8;
            acc0 = acc0 + feat8[srcb + f];
            acc1 = acc1 + feat8[srcb + 4 + f];
        }
        acc0 = acc0 + shflx8(acc0, 4);
        acc1 = acc1 + shflx8(acc1, 4);
        acc0 = acc0 + shflx8(acc0, 8);
        acc1 = acc1 + shflx8(acc1, 8);
        acc0 = acc0 + shflx8(acc0, 16);
        acc1 = acc1 + shflx8(acc1, 16);
        _Float16 inv = (_Float16)(1.0f / (float)max(r1 - r0, 1));
        h8 iv = { inv, inv, inv, inv, inv, inv, inv, inv };
        if (sub == 0) {
            ag8[(unsigned)(node * 16 + list * 8 + f)]     = acc0 * iv;
            ag8[(unsigned)(node * 16 + list * 8 + 4 + f)] = acc1 * iv;
        }
    }
}

// --------------------------------- GEMM ------------------------------------
// [64 nodes x 192] @ [192 x 64] per block (4 waves x 16-node tiles).
// A staged in LDS (row stride 200 fp16). D layout (verified):
// col = lane&15, row = (lane>>4)*4 + reg.

#define ROWP 200

__global__ void __launch_bounds__(256) gemm_k(
    const h8* __restrict__ ag8, const h8* __restrict__ feat8,
    const h8* __restrict__ Bp,
    const float* __restrict__ bp, const float* __restrict__ bn,
    float* __restrict__ outf, _Float16* __restrict__ outh,
    int f32out, int n)
{
    __shared__ _Float16 A_lds[64 * ROWP];   // 25.6 KB
    int tid = threadIdx.x;
    int base = blockIdx.x * 64;

    // stage A: per row, 16 h8 chunks of ag (128 h) + 8 h8 chunks of feat (64 h)
    for (int ch = tid; ch < 64 * 24; ch += 256) {
        int r = ch / 24, p = ch % 24;
        int row = min(base + r, n - 1);
        h8 v = (p < 16) ? ag8[(size_t)row * 16 + p]
                        : feat8[(size_t)row * 8 + (p - 16)];
        *(h8*)&A_lds[r * ROWP + p * 8] = v;
    }
    __syncthreads();

    int w = tid >> 6, lane = tid & 63;
    int m = lane & 15, g = lane >> 4;

    h8 a[6];
    #pragma unroll
    for (int kk = 0; kk < 6; ++kk)
        a[kk] = *(const h8*)&A_lds[(w * 16 + m) * ROWP + kk * 32 + g * 8];

    #pragma unroll
    for (int nt = 0; nt < 4; ++nt) {
        f32x4 acc = { 0.f, 0.f, 0.f, 0.f };
        #pragma unroll
        for (int kk = 0; kk < 6; ++kk) {
            h8 b = Bp[(kk * 4 + nt) * 64 + lane];
            acc = __builtin_amdgcn_mfma_f32_16x16x32_f16(a[kk], b, acc, 0, 0, 0);
        }
        int colc = nt * 16 + m;
        float bias = (colc < 32) ? bp[colc] : bn[colc - 32];
        #pragma unroll
        for (int reg = 0; reg < 4; ++reg) {
            int node = base + w * 16 + g * 4 + reg;
            if (node < n) {
                float val = fast_tanh(acc[reg] + bias);
                if (f32out) outf[(size_t)node * 64 + colc] = val;
                else        outh[(size_t)node * 64 + colc] = (_Float16)val;
            }
        }
    }
}

extern "C" void kernel_launch(void* const* d_in, const int* in_sizes, int n_in,
                              void* d_out, int out_size, void* d_ws, size_t ws_size,
                              hipStream_t stream)
{
    const float* x   = (const float*)d_in[0];
    const float* W1p = (const float*)d_in[1];
    const float* b1p = (const float*)d_in[2];
    const float* W1n = (const float*)d_in[3];
    const float* b1n = (const float*)d_in[4];
    const float* W2p = (const float*)d_in[5];
    const float* b2p = (const float*)d_in[6];
    const float* W2n = (const float*)d_in[7];
    const float* b2n = (const float*)d_in[8];
    const int*   pos = (const int*)d_in[9];
    const int*   neg = (const int*)d_in[10];

    int n = in_sizes[0] / 64;       // 100000
    int E = in_sizes[9] / 2;        // 1250000
    int n2 = 2 * n;
    int nb = (n2 + BSIZE - 1) / BSIZE;   // 391 buckets

    // ws: pcnt[512] | cur[2n] | col[2E] | Bpack[2*24*64*8 h] | xh[n*64 h] |
    //     U = max(ebuf nb*CAP u32, zh n*64 h)
    // ag (n x 128 h = 25.6MB) lives in d_out (each gemm block reads exactly
    // the ag rows it later overwrites).
    int*      pcnt  = (int*)d_ws;
    int*      cur   = pcnt + NBMAX;
    int*      col   = cur + n2;
    _Float16* Bpack = (_Float16*)(col + 2 * (size_t)E);
    _Float16* xh    = Bpack + 2 * 24 * 64 * 8;
    unsigned* ebuf  = (unsigned*)(xh + (size_t)n * 64);
    _Float16* zh    = (_Float16*)ebuf;            // aliases ebuf (dead after scatter)
    h8*       ag8   = (h8*)d_out;

    hipMemsetAsync(pcnt, 0, NBMAX * sizeof(int), stream);

    int bblocks = (2 * E + 8191) / 8192;
    int n4 = n * 16;
    int cvtBlocks = (n4 + 255) / 256;

    mega_k<<<bblocks + cvtBlocks + 12, 256, 0, stream>>>(
        pos, neg, pcnt, ebuf, E, n, nb, bblocks,
        (const float4*)x, (h4*)xh, n4, cvtBlocks,
        W1p, W1n, W2p, W2n, Bpack);

    scatter_k<<<nb, 256, 0, stream>>>(ebuf, pcnt, cur, col, n, nb);

    int ablocks = 2048;
    int gblocks = (n + 63) / 64;

    // layer 1: agg(x) -> ag ; gemm(A1=[ag|x]) -> zh (fp16)
    agg_k <<<ablocks, 256, 0, stream>>>((const h8*)xh, cur, col, ag8, n);
    gemm_k<<<gblocks, 256, 0, stream>>>(ag8, (const h8*)xh, (const h8*)Bpack,
                                        b1p, b1n, nullptr, zh, 0, n);

    // layer 2: agg(z) -> ag ; gemm(A2=[Mp|Mn|z]) -> out (fp32)
    agg_k <<<ablocks, 256, 0, stream>>>((const h8*)zh, cur, col, ag8, n);
    gemm_k<<<gblocks, 256, 0, stream>>>(ag8, (const h8*)zh,
                                        (const h8*)(Bpack + 24 * 64 * 8),
                                        b2p, b2n, (float*)d_out, nullptr, 1, n);
}